// Round 16
// baseline (35.991 us; speedup 1.0000x reference)
//
#include <hip/hip_runtime.h>

// Volume rendering composite (cumprod along chunk-row axis, per-column).
// s[b,p] = density*delta >= 0; T = exp(-prefix(s)); monotone prefix =>
// exp(-S)==0 exactly in fp32 for S>110, so late contributions are exactly 0.
//
// PROVEN: small dependent dispatches (grid-wide sync ruled out: R7 fence
// 248us, R11 cooperative 267us; no hipMemsetAsync: 57us fill). Bytes are
// the lever (R13 half-scan -6.7us matched; R15 -1.9us matched 8MB cut).
// K2 TLP neutral 3x -> live phase is not occupancy-bound.
//
// R16: kill K2's per-block prefix rebuild. New tiny K1s scan kernel
// computes the exclusive column-prefix over superblock sums (in place,
// 8 blocks x 128 thr, L2-resident) + total at slot [NSBH]. K2 reads its
// exact base with ONE float2 load; dead blocks (71%) exit immediately.
// Also NSBH 48->44 (rows<2816: S ~ 131 +- 3.2, min col ~122 >> 110).
//   K1  seg_sum: rows < NSBH*64; 4-row quarter-segment sums -> wsA,
//                superblock sums -> wsBS[k], k<NSBH.
//   K1s scan:    wsBS[k] <- exclusive prefix; wsBS[NSBH] <- total.
//   K2  composite: base = wsBS[min(sb,NSBH)] (1 float2 read); dead ->
//                zero partial, exit. Live lower: intra-block seg prefix
//                from wsA; live upper (adversarial only): serial fallback.
//   K3  reduce:  fixed-order sum over partials -> d_out.

#define P 128
#define FARD 1.0e10f
#define SKIP_S 110.0f
#define SB 8           // waves per K1 block (8-row ranges); superblock = 64 rows
#define NSBH 44        // superblocks scanned by K1 (rows < 2816)
#define QSEG 16        // 4-row quarter-segments per superblock

__global__ __launch_bounds__(512) void seg_sum_kernel(
    const float* __restrict__ density,
    const float* __restrict__ depth,
    float* __restrict__ wsA,    // [c][sb<NSBH][QSEG][P] 4-row segment sums
    float* __restrict__ wsBS,   // [c][NSBH+1][P] superblock sums -> prefixes
    int chunk)
{
    __shared__ float2 ls[SB][64];
    const int w = threadIdx.x >> 6;               // 8-row range within block
    const int t = threadIdx.x & 63;               // lane -> cols 2t, 2t+1
    const int sb = blockIdx.x, c = blockIdx.y;
    const long long row0 = (long long)c * chunk + ((long long)sb * SB + w) * 8;
    const float2* __restrict__ d2 = (const float2*)density;
    const float2* __restrict__ z2 = (const float2*)depth;
    float sx0 = 0.f, sy0 = 0.f, sx1 = 0.f, sy1 = 0.f;
    #pragma unroll
    for (int r = 0; r < 8; ++r) {
        const long long h = (row0 + r) * (P / 2) + t;
        float2 d = d2[h];
        float2 z = z2[h];
        float zn = __shfl_down(z.x, 1);           // depth[b, 2t+2]
        float ax = d.x * (z.y - z.x);
        float ay = d.y * ((t == 63) ? FARD : (zn - z.y));
        if (r < 4) { sx0 += ax; sy0 += ay; }
        else       { sx1 += ax; sy1 += ay; }
    }
    float2* wa2 = (float2*)wsA;
    const long long qb = (((long long)c * NSBH + sb) * QSEG + 2 * w) * 64 + t;
    float2 o0; o0.x = sx0; o0.y = sy0;
    float2 o1; o1.x = sx1; o1.y = sy1;
    wa2[qb] = o0;
    wa2[qb + 64] = o1;
    float2 oT; oT.x = sx0 + sx1; oT.y = sy0 + sy1;
    ls[w][t] = oT;
    __syncthreads();
    if (w == 0) {
        float bx = 0.f, by = 0.f;
        #pragma unroll
        for (int k = 0; k < SB; ++k) { bx += ls[k][t].x; by += ls[k][t].y; }
        float2 b; b.x = bx; b.y = by;
        ((float2*)wsBS)[((long long)c * (NSBH + 1) + sb) * (P / 2) + t] = b;
    }
}

// In-place exclusive column prefix over NSBH superblock sums; total -> [NSBH].
__global__ __launch_bounds__(128) void scan_kernel(float* __restrict__ wsBS)
{
    const int c = blockIdx.x, p = threadIdx.x;
    const long long base = (long long)c * (NSBH + 1) * P + p;
    float run = 0.f;
    #pragma unroll 4
    for (int k = 0; k < NSBH; ++k) {
        const long long i = base + (long long)k * P;
        float v = wsBS[i];
        wsBS[i] = run;
        run += v;
    }
    wsBS[base + (long long)NSBH * P] = run;
}

__global__ __launch_bounds__(1024) void composite_kernel(
    const float* __restrict__ density,
    const float* __restrict__ feature,
    const float* __restrict__ depth,
    const float* __restrict__ wsA,
    const float* __restrict__ wsBS,
    float* __restrict__ wsB,    // [c][sb][512] partials
    int nsb, int chunk)
{
    __shared__ float seg[QSEG][P];
    __shared__ float red[QSEG][512];
    __shared__ int alive;
    const int tid = threadIdx.x;
    const int w = tid >> 6, t = tid & 63;         // 16 waves; 4-row segments
    const int c = blockIdx.x, sb = blockIdx.y;    // transposed grid

    // Exact prefix base (or lower bound for upper blocks): ONE float2 read.
    const int kidx = (sb < NSBH) ? sb : NSBH;
    float2 bse = ((const float2*)wsBS)[((long long)c * (NSBH + 1) + kidx) * (P / 2) + t];

    if (tid == 0) alive = 0;
    __syncthreads();
    if ((bse.x <= SKIP_S) || (bse.y <= SKIP_S)) alive = 1;  // benign race
    __syncthreads();

    if (!alive) {                                 // whole block exactly dead
        if (tid < 512) wsB[((long long)c * nsb + sb) * 512 + tid] = 0.f;
        return;
    }

    const float2* __restrict__ d2 = (const float2*)density;
    const float2* __restrict__ z2 = (const float2*)depth;
    const int p0 = 2 * t;
    float Sx, Sy;

    if (sb < NSBH) {
        // 16 quarter-segment sums -> LDS (2 coalesced loads per thread).
        {
            int idx = tid;
            seg[idx >> 7][idx & (P - 1)] =
                wsA[(((long long)c * NSBH + sb) * QSEG + (idx >> 7)) * P + (idx & (P - 1))];
            idx = tid + 1024;
            seg[idx >> 7][idx & (P - 1)] =
                wsA[(((long long)c * NSBH + sb) * QSEG + (idx >> 7)) * P + (idx & (P - 1))];
        }
        __syncthreads();
        Sx = bse.x; Sy = bse.y;
        for (int k = 0; k < w; ++k) { Sx += seg[k][p0]; Sy += seg[k][p0 + 1]; }
    } else {
        // Fallback (never taken for realistic data): exact base by scanning
        // rows K1 skipped: [NSBH*64, this segment's first row).
        Sx = bse.x; Sy = bse.y;
        const long long cb = (long long)c * chunk;
        const long long rowH = (long long)NSBH * 64;
        const long long rowStart = (long long)sb * 64 + (long long)w * 4;
        for (long long r = rowH; r < rowStart; ++r) {
            const long long h = (cb + r) * (P / 2) + t;
            float2 d = d2[h];
            float2 z = z2[h];
            float zn = __shfl_down(z.x, 1);
            Sx += d.x * (z.y - z.x);
            Sy += d.y * ((t == 63) ? FARD : (zn - z.y));
        }
    }

    float fa0 = 0.f, fa1 = 0.f, fa2 = 0.f;
    float fb0 = 0.f, fb1 = 0.f, fb2 = 0.f;
    float da = 0.f, db = 0.f;

    const bool dead = __all((Sx > SKIP_S) && (Sy > SKIP_S));
    if (!dead) {
        const long long row0 = (long long)c * chunk + (long long)sb * 64 + (long long)w * 4;
        const float2* __restrict__ f2 = (const float2*)feature;
        float tx = __expf(-Sx), ty = __expf(-Sy);  // T at segment start
        #pragma unroll
        for (int r = 0; r < 4; ++r) {
            const long long hh = (row0 + r) * (P / 2) + t;
            float2 d = d2[hh];
            float2 z = z2[hh];
            float zn = __shfl_down(z.x, 1);
            float sx = d.x * (z.y - z.x);
            float sy = d.y * ((t == 63) ? FARD : (zn - z.y));
            float ex = __expf(-sx), ey = __expf(-sy);
            float tnx = tx * ex, tny = ty * ey;   // running cumprod, as ref
            float wx = tx - tnx;                  // T_i * (1 - temp_i)
            float wy = ty - tny;
            tx = tnx; ty = tny;
            const long long fi = 3 * hh;
            float2 f01 = f2[fi], f23 = f2[fi + 1], f45 = f2[fi + 2];
            fa0 += wx * f01.x; fa1 += wx * f01.y; fa2 += wx * f23.x;
            fb0 += wy * f23.y; fb1 += wy * f45.x; fb2 += wy * f45.y;
            da  += wx * z.x;   db  += wy * z.y;
        }
    }

    // Per-wave partials -> LDS. Layout per wave: [p*3+comp | 384+p].
    float* rw = red[w];
    rw[p0 * 3 + 0] = fa0; rw[p0 * 3 + 1] = fa1; rw[p0 * 3 + 2] = fa2;
    rw[p0 * 3 + 3] = fb0; rw[p0 * 3 + 4] = fb1; rw[p0 * 3 + 5] = fb2;
    rw[384 + p0] = da;    rw[384 + p0 + 1] = db;
    __syncthreads();

    if (tid < 512) {
        float s = 0.f;
        #pragma unroll
        for (int k = 0; k < QSEG; ++k) s += red[k][tid];
        wsB[((long long)c * nsb + sb) * 512 + tid] = s;
    }
}

__global__ __launch_bounds__(64) void reduce_kernel(
    const float* __restrict__ wsB,
    float* __restrict__ out,
    int nsb, int n_chunks)
{
    const int b = blockIdx.x;                     // 8 blocks per chunk
    const int c = b >> 3, q = b & 7;
    const int e = q * 64 + threadIdx.x;           // 0..511
    float s = 0.f;
    #pragma unroll 4
    for (int sb = 0; sb < nsb; ++sb)
        s += wsB[((long long)c * nsb + sb) * 512 + e];
    if (e < 384) out[(long long)c * 384 + e] = s;                    // feat
    else out[(long long)n_chunks * 384 + (long long)c * P + (e - 384)] = s;
}

extern "C" void kernel_launch(void* const* d_in, const int* in_sizes, int n_in,
                              void* d_out, int out_size, void* d_ws, size_t ws_size,
                              hipStream_t stream)
{
    const float* density = (const float*)d_in[0];
    const float* feature = (const float*)d_in[1];
    const float* depth   = (const float*)d_in[2];
    float* out = (float*)d_out;

    const int B = in_sizes[0] / P;        // 65536
    const int chunk = 8192;               // matches setup_inputs() chunk_size
    const int n_chunks = B / chunk;       // 8
    const int nsb = chunk / 64;           // 128 superblocks per chunk

    float* wsA  = (float*)d_ws;                                  // 2.75 MB
    float* wsBS = wsA + (size_t)n_chunks * NSBH * QSEG * P;      // 0.18 MB
    float* wsB  = wsBS + (size_t)n_chunks * (NSBH + 1) * P;      // 2 MB

    dim3 grid1(NSBH, n_chunks);
    seg_sum_kernel<<<grid1, 512, 0, stream>>>(density, depth, wsA, wsBS, chunk);
    scan_kernel<<<n_chunks, P, 0, stream>>>(wsBS);
    dim3 grid2(n_chunks, nsb);            // transposed: live blocks contiguous
    composite_kernel<<<grid2, 1024, 0, stream>>>(density, feature, depth,
                                                 wsA, wsBS, wsB, nsb, chunk);
    reduce_kernel<<<n_chunks * 8, 64, 0, stream>>>(wsB, out, nsb, n_chunks);
}

// Round 18
// 34.694 us; speedup vs baseline: 1.0374x; 1.0374x over previous
//
#include <hip/hip_runtime.h>

// Volume rendering composite (cumprod along chunk-row axis, per-column).
//
// R17 RESTRUCTURE (resubmit; two infra failures): ONE dispatch. The
// row-split designs (R3-R16) created a cross-block prefix dependency
// costing 3-4 dependent dispatches at ~4-5us each (R16 calibrated:
// +1 dispatch = +4us; grid-wide sync is 100+us, R7/R11). But the 1024
// (chunk x column) scans are fully INDEPENDENT: one lane per column
// walks rows serially, carrying T = cumprod(exp(-s)) exactly as the
// reference does, accumulating feat/depth in registers and writing
// d_out directly. No workspace, no atomics, no fences, no memsets.
//
// Early exit: remaining contributions after T drops below EPS sum to
// exactly T (telescoping), so exiting at T < 1e-12 bounds the output
// error by ~8e-12 (|feature|<1, depth<8) vs the 0.16 harness threshold.
// Data: T < 1e-12 at ~600 of 8192 rows. Adversarial data that never
// underflows just runs the full scan (correct, slower). Checked every
// 64 rows (wave-uniform __all), so the hot loop is branch-free.
//
// Parallelism: 16 blocks x 64 lanes = 8 chunks x 128 columns. Per row a
// wave issues 5 coalesced loads (d, z, z+1, f as float3); loads across
// rows are independent (addresses affine in b) so they pipeline; the only
// serial dependency is T *= e (1 mul, ~4 cyc) -> ~2.5k cycles per wave.

#define P 128
#define FARD 1.0e10f
#define EPS 1.0e-12f

__global__ __launch_bounds__(64) void render_kernel(
    const float* __restrict__ density,
    const float* __restrict__ feature,
    const float* __restrict__ depth,
    float* __restrict__ out,
    int chunk, int n_chunks)
{
    const int t = threadIdx.x;
    const int c = blockIdx.x >> 1;                   // chunk
    const int p = ((blockIdx.x & 1) << 6) + t;       // column 0..127
    const long long rbase = (long long)c * chunk;

    float T = 1.f;
    float fa0 = 0.f, fa1 = 0.f, fa2 = 0.f, da = 0.f;
    const bool far = (p == P - 1);

    for (int bb = 0; bb < chunk; bb += 64) {
        #pragma unroll 8
        for (int b = bb; b < bb + 64; ++b) {
            const long long h = (rbase + b) * P + p;
            float d = density[h];
            float z = depth[h];
            // lane for col 127 must not read h+1 (last element is OOB+1);
            // its delta is the FAR sentinel anyway.
            float zn = depth[far ? h : h + 1];
            float s = d * (far ? FARD : (zn - z));
            float e = __expf(-s);
            float Tn = T * e;                        // running cumprod (ref)
            float w = T - Tn;                        // T_i * (1 - temp_i)
            T = Tn;
            float3 f = ((const float3*)feature)[h];
            fa0 += w * f.x; fa1 += w * f.y; fa2 += w * f.z;
            da  += w * z;
        }
        if (__all(T < EPS)) break;                   // telescoping bound
    }

    float* fo = out + ((long long)c * P + p) * 3;
    fo[0] = fa0; fo[1] = fa1; fo[2] = fa2;
    out[(long long)n_chunks * P * 3 + (long long)c * P + p] = da;
}

extern "C" void kernel_launch(void* const* d_in, const int* in_sizes, int n_in,
                              void* d_out, int out_size, void* d_ws, size_t ws_size,
                              hipStream_t stream)
{
    const float* density = (const float*)d_in[0];
    const float* feature = (const float*)d_in[1];
    const float* depth   = (const float*)d_in[2];
    float* out = (float*)d_out;

    const int B = in_sizes[0] / P;        // 65536
    const int chunk = 8192;               // matches setup_inputs() chunk_size
    const int n_chunks = B / chunk;       // 8

    render_kernel<<<n_chunks * 2, 64, 0, stream>>>(density, feature, depth,
                                                   out, chunk, n_chunks);
}

// Round 23
// 32.937 us; speedup vs baseline: 1.0927x; 1.0533x over previous
//
#include <hip/hip_runtime.h>

// Volume rendering composite (cumprod along chunk-row axis, per-column).
//
// R19 (4th resubmit; four consecutive infra failures, error precedes
// compile): ONE dispatch (R17) + intra-block row parallelism. R17's
// lane-per-column serial scan was latency-bound: 16 waves total, 0.2%
// VALUBusy, ~35us. Here each block (1024 thr = 16 waves) owns (chunk,
// col-half) and processes a 1024-row window per iteration: wave w scans
// a 64-row strip (phase A: per-column strip sums sigma_w), LDS-scan
// stitches the 16 strips, phase B re-walks the strip (L2-hot)
// compositing with T_start = T_win * exp(-prefix_w). Early exit when all
// columns' T < EPS: residual contributions telescope to exactly
// T < 1e-12 -> error <= 8e-12 (|f|<=1, z<8) vs the 0.16 threshold. This
// data: T ~ e^-47 after window 0 -> exactly 1 iteration; adversarial
// data runs more windows (exact). No workspace, no atomics, no fences,
// no memsets, no cross-block deps.

#define P 128
#define FARD 1.0e10f
#define EPS 1.0e-12f
#define WAVES 16
#define WROWS 64
#define WIN (WAVES * WROWS)   // 1024-row window

__global__ __launch_bounds__(1024) void render_kernel(
    const float* __restrict__ density,
    const float* __restrict__ feature,
    const float* __restrict__ depth,
    float* __restrict__ out,
    int chunk, int n_chunks)
{
    __shared__ float sig[WAVES][64];
    __shared__ float Tcur[64];
    __shared__ float acc[WAVES][64][4];           // 16 KB
    __shared__ int done;
    const int tid = threadIdx.x;
    const int w = tid >> 6, t = tid & 63;
    const int c = blockIdx.x >> 1;                // chunk
    const int half = blockIdx.x & 1;
    const int col = half * 64 + t;                // this lane's column
    const bool far = (col == P - 1);
    const long long cbase = (long long)c * chunk;

    if (w == 0) Tcur[t] = 1.f;
    float fa0 = 0.f, fa1 = 0.f, fa2 = 0.f, da = 0.f;
    __syncthreads();

    const int nwin = chunk / WIN;                 // 8
    for (int it = 0; it < nwin; ++it) {
        const long long r0 = cbase + (long long)it * WIN + w * WROWS;

        // Phase A: per-column strip sum (64 rows).
        float sg = 0.f;
        #pragma unroll 8
        for (int r = 0; r < WROWS; ++r) {
            const long long h = (r0 + r) * P + col;
            float d = density[h];
            float z = depth[h];
            float zn = __shfl_down(z, 1);         // next column's z, same row
            if (t == 63) zn = far ? z : depth[h + 1];
            sg += d * (far ? FARD : (zn - z));
        }
        sig[w][t] = sg;
        __syncthreads();

        // Stitch: exclusive prefix over the 16 strips for this column.
        float pre = 0.f;
        for (int k = 0; k < w; ++k) pre += sig[k][t];
        float Trun = Tcur[t] * __expf(-pre);      // T at strip start

        // Phase B: composite the strip (reload d/z L2-hot; read feature).
        #pragma unroll 4
        for (int r = 0; r < WROWS; ++r) {
            const long long h = (r0 + r) * P + col;
            float d = density[h];
            float z = depth[h];
            float zn = __shfl_down(z, 1);
            if (t == 63) zn = far ? z : depth[h + 1];
            float s = d * (far ? FARD : (zn - z));
            float e = __expf(-s);
            float Tn = Trun * e;                  // running cumprod (ref)
            float wt = Trun - Tn;                 // T_i * (1 - temp_i)
            Trun = Tn;
            const float* f = feature + 3 * h;
            fa0 += wt * f[0]; fa1 += wt * f[1]; fa2 += wt * f[2];
            da  += wt * z;
        }
        __syncthreads();                          // everyone done with Tcur
        if (w == WAVES - 1) Tcur[t] = Trun;       // window-end T
        if (tid == 0) done = 1;
        __syncthreads();
        if (w == 0 && !(Tcur[t] < EPS)) done = 0; // benign divergent store
        __syncthreads();
        if (done) break;                          // telescoping bound
    }

    // Reduce the 16 waves' accumulators (fixed order) and write out.
    acc[w][t][0] = fa0; acc[w][t][1] = fa1; acc[w][t][2] = fa2; acc[w][t][3] = da;
    __syncthreads();
    if (w < 4) {                                  // component w for column t
        float s = 0.f;
        #pragma unroll
        for (int k = 0; k < WAVES; ++k) s += acc[k][t][w];
        if (w < 3) out[((long long)c * P + col) * 3 + w] = s;
        else out[(long long)n_chunks * P * 3 + (long long)c * P + col] = s;
    }
}

extern "C" void kernel_launch(void* const* d_in, const int* in_sizes, int n_in,
                              void* d_out, int out_size, void* d_ws, size_t ws_size,
                              hipStream_t stream)
{
    const float* density = (const float*)d_in[0];
    const float* feature = (const float*)d_in[1];
    const float* depth   = (const float*)d_in[2];
    float* out = (float*)d_out;

    const int B = in_sizes[0] / P;        // 65536
    const int chunk = 8192;               // matches setup_inputs() chunk_size
    const int n_chunks = B / chunk;       // 8

    render_kernel<<<n_chunks * 2, 1024, 0, stream>>>(density, feature, depth,
                                                     out, chunk, n_chunks);
}

// Round 24
// 23.631 us; speedup vs baseline: 1.5231x; 1.3938x over previous
//
#include <hip/hip_runtime.h>

// Volume rendering composite (cumprod along chunk-row axis, per-column).
//
// R24: floor-test refinement of the 1-dispatch design. R23 measured 32.9us
// vs R15's 3-dispatch 32.0us (tied); counters show latency-stall-bound on
// 16 CUs (VALUBusy ~8% of active CUs). Two critical-path cuts:
//  (1) window 1024 -> 256 rows (16 waves x 16-row strips): early-exit
//      checks 4x more often -> walk ~768 rows not 1024 (live ends where
//      S > 27.6: T < 1e-12, residual telescopes to < 8e-12 error).
//  (2) phase A caches e = exp(-s) in LDS (256x64 = 64 KB); phase B reads
//      e from LDS + loads only z (L2-hot) and feature -> per-row global
//      loads 7 -> 6, one exp instead of two, no shuffle in phase B.
// If this lands ~32-33 unchanged, the remaining time is harness/replay
// floor, not kernel — all designs since R15 are within noise of it.

#define P 128
#define FARD 1.0e10f
#define EPS 1.0e-12f
#define WAVES 16
#define WROWS 16
#define WIN (WAVES * WROWS)   // 256-row window

__global__ __launch_bounds__(1024) void render_kernel(
    const float* __restrict__ density,
    const float* __restrict__ feature,
    const float* __restrict__ depth,
    float* __restrict__ out,
    int chunk, int n_chunks)
{
    __shared__ float es[WIN][64];                 // 64 KB: e per (row, col)
    __shared__ float sig[WAVES][64];
    __shared__ float Tcur[64];
    __shared__ float acc[WAVES][64][4];           // 16 KB
    __shared__ int done;
    const int tid = threadIdx.x;
    const int w = tid >> 6, t = tid & 63;
    const int c = blockIdx.x >> 1;                // chunk
    const int half = blockIdx.x & 1;
    const int col = half * 64 + t;                // this lane's column
    const bool far = (col == P - 1);
    const long long cbase = (long long)c * chunk;

    if (w == 0) Tcur[t] = 1.f;
    float fa0 = 0.f, fa1 = 0.f, fa2 = 0.f, da = 0.f;
    __syncthreads();

    const int nwin = chunk / WIN;                 // 32
    for (int it = 0; it < nwin; ++it) {
        const long long r0 = cbase + (long long)it * WIN + w * WROWS;

        // Phase A: strip sum of s; cache e = exp(-s) in LDS.
        float sg = 0.f;
        #pragma unroll 4
        for (int r = 0; r < WROWS; ++r) {
            const long long h = (r0 + r) * P + col;
            float d = density[h];
            float z = depth[h];
            float zn = __shfl_down(z, 1);         // next column's z, same row
            if (t == 63) zn = far ? z : depth[h + 1];
            float s = d * (far ? FARD : (zn - z));
            es[w * WROWS + r][t] = __expf(-s);
            sg += s;
        }
        sig[w][t] = sg;
        __syncthreads();

        // Stitch: exclusive prefix over the 16 strips for this column.
        float pre = 0.f;
        for (int k = 0; k < w; ++k) pre += sig[k][t];
        float Trun = Tcur[t] * __expf(-pre);      // T at strip start

        // Phase B: composite from LDS e + L2-hot z + feature.
        #pragma unroll 4
        for (int r = 0; r < WROWS; ++r) {
            const long long h = (r0 + r) * P + col;
            float z = depth[h];
            float e = es[w * WROWS + r][t];
            float Tn = Trun * e;                  // running cumprod (ref)
            float wt = Trun - Tn;                 // T_i * (1 - temp_i)
            Trun = Tn;
            const float* f = feature + 3 * h;
            fa0 += wt * f[0]; fa1 += wt * f[1]; fa2 += wt * f[2];
            da  += wt * z;
        }
        __syncthreads();                          // all done with es/Tcur
        if (w == WAVES - 1) Tcur[t] = Trun;       // window-end T
        if (tid == 0) done = 1;
        __syncthreads();
        if (w == 0 && !(Tcur[t] < EPS)) done = 0; // benign divergent store
        __syncthreads();
        if (done) break;                          // telescoping bound
    }

    // Reduce the 16 waves' accumulators (fixed order) and write out.
    acc[w][t][0] = fa0; acc[w][t][1] = fa1; acc[w][t][2] = fa2; acc[w][t][3] = da;
    __syncthreads();
    if (w < 4) {                                  // component w for column t
        float s = 0.f;
        #pragma unroll
        for (int k = 0; k < WAVES; ++k) s += acc[k][t][w];
        if (w < 3) out[((long long)c * P + col) * 3 + w] = s;
        else out[(long long)n_chunks * P * 3 + (long long)c * P + col] = s;
    }
}

extern "C" void kernel_launch(void* const* d_in, const int* in_sizes, int n_in,
                              void* d_out, int out_size, void* d_ws, size_t ws_size,
                              hipStream_t stream)
{
    const float* density = (const float*)d_in[0];
    const float* feature = (const float*)d_in[1];
    const float* depth   = (const float*)d_in[2];
    float* out = (float*)d_out;

    const int B = in_sizes[0] / P;        // 65536
    const int chunk = 8192;               // matches setup_inputs() chunk_size
    const int n_chunks = B / chunk;       // 8

    render_kernel<<<n_chunks * 2, 1024, 0, stream>>>(density, feature, depth,
                                                     out, chunk, n_chunks);
}

// Round 25
// 21.226 us; speedup vs baseline: 1.6956x; 1.1133x over previous
//
#include <hip/hip_runtime.h>

// Volume rendering composite (cumprod along chunk-row axis, per-column).
//
// R25: register-resident strips. R24 (23.6us) proved the kernel still
// dominates; it also wastefully round-tripped e through LDS although the
// SAME lane computes and consumes it. Now: per 128-row window (16 waves x
// 8-row strips), each lane batch-loads its strip's d/z/feature (40 loads
// in flight, feature HBM latency overlapped with strip-sum compute),
// keeps e in registers, stitches strip sums via one LDS buffer with ONE
// barrier per window (sig double-buffered -> no WAR barrier; Tcur is a
// per-thread register identically computed by every wave, so the
// early-exit predicate __all(Tcur<EPS) is block-uniform with no flag
// protocol). Phase B is pure register compute: zero loads, zero LDS.
// Early exit: residual telescopes to T < 1e-12 -> error <= 8e-12
// (|f|<=1, z<8) vs 0.16 threshold. Adversarial data: more windows, exact.
// ONE dispatch, no workspace, no atomics, no fences, no memsets.

#define P 128
#define FARD 1.0e10f
#define EPS 1.0e-12f
#define WAVES 16
#define WROWS 8
#define WIN (WAVES * WROWS)   // 128-row window

__global__ __launch_bounds__(1024) void render_kernel(
    const float* __restrict__ density,
    const float* __restrict__ feature,
    const float* __restrict__ depth,
    float* __restrict__ out,
    int chunk, int n_chunks)
{
    __shared__ float sig[2][WAVES][64];           // 8 KB, double-buffered
    __shared__ float acc[WAVES][64][4];           // 16 KB
    const int tid = threadIdx.x;
    const int w = tid >> 6, t = tid & 63;
    const int c = blockIdx.x >> 1;                // chunk
    const int half = blockIdx.x & 1;
    const int col = half * 64 + t;                // this lane's column
    const bool far = (col == P - 1);
    const long long cbase = (long long)c * chunk;

    float Tcur = 1.f;                             // identical across waves
    float fa0 = 0.f, fa1 = 0.f, fa2 = 0.f, da = 0.f;

    const int nwin = chunk / WIN;                 // 64
    for (int it = 0; it < nwin; ++it) {
        const long long r0 = cbase + (long long)it * WIN + (long long)w * WROWS;

        // Batch-load the whole strip: d, z, feature (latency overlapped).
        float dv[WROWS], zv[WROWS], ev[WROWS];
        float f0[WROWS], f1[WROWS], f2[WROWS];
        #pragma unroll
        for (int r = 0; r < WROWS; ++r) {
            const long long h = (r0 + r) * P + col;
            dv[r] = density[h];
            zv[r] = depth[h];
            const float* f = feature + 3 * h;
            f0[r] = f[0]; f1[r] = f[1]; f2[r] = f[2];
        }
        // Strip sum + per-row e in registers.
        float sg = 0.f;
        #pragma unroll
        for (int r = 0; r < WROWS; ++r) {
            float zn = __shfl_down(zv[r], 1);     // next column's z, same row
            if (t == 63) zn = far ? zv[r] : depth[(r0 + r) * P + col + 1];
            float s = dv[r] * (far ? FARD : (zn - zv[r]));
            ev[r] = __expf(-s);
            sg += s;
        }
        sig[it & 1][w][t] = sg;
        __syncthreads();                          // the window's ONE barrier

        // Stitch: exclusive prefix (this wave) + window total (for Tcur).
        float pre = 0.f, total = 0.f;
        #pragma unroll
        for (int k = 0; k < WAVES; ++k) {
            float v = sig[it & 1][k][t];
            if (k < w) pre += v;
            total += v;
        }
        float Trun = Tcur * __expf(-pre);         // T at strip start

        // Composite: pure register compute.
        #pragma unroll
        for (int r = 0; r < WROWS; ++r) {
            float Tn = Trun * ev[r];              // running cumprod (ref)
            float wt = Trun - Tn;                 // T_i * (1 - temp_i)
            Trun = Tn;
            fa0 += wt * f0[r]; fa1 += wt * f1[r]; fa2 += wt * f2[r];
            da  += wt * zv[r];
        }

        Tcur *= __expf(-total);                   // window-end T (uniform)
        if (__all(Tcur < EPS)) break;             // telescoping bound
    }

    // Reduce the 16 waves' accumulators (fixed order) and write out.
    acc[w][t][0] = fa0; acc[w][t][1] = fa1; acc[w][t][2] = fa2; acc[w][t][3] = da;
    __syncthreads();
    if (w < 4) {                                  // component w for column t
        float s = 0.f;
        #pragma unroll
        for (int k = 0; k < WAVES; ++k) s += acc[k][t][w];
        if (w < 3) out[((long long)c * P + col) * 3 + w] = s;
        else out[(long long)n_chunks * P * 3 + (long long)c * P + col] = s;
    }
}

extern "C" void kernel_launch(void* const* d_in, const int* in_sizes, int n_in,
                              void* d_out, int out_size, void* d_ws, size_t ws_size,
                              hipStream_t stream)
{
    const float* density = (const float*)d_in[0];
    const float* feature = (const float*)d_in[1];
    const float* depth   = (const float*)d_in[2];
    float* out = (float*)d_out;

    const int B = in_sizes[0] / P;        // 65536
    const int chunk = 8192;               // matches setup_inputs() chunk_size
    const int n_chunks = B / chunk;       // 8

    render_kernel<<<n_chunks * 2, 1024, 0, stream>>>(density, feature, depth,
                                                     out, chunk, n_chunks);
}